// Round 8
// baseline (138.508 us; speedup 1.0000x reference)
//
#include <hip/hip_runtime.h>

#define TPB 512

__global__ __launch_bounds__(TPB, 8) void fused_shift_conv(const float* __restrict__ x,
                                                           const float* __restrict__ Wg,
                                                           float* __restrict__ out) {
    // block handles (n, 2 output rows p0, p0+1)
    const int bid = blockIdx.x;
    const int ptile = bid % 28;
    const int n = bid / 28;
    const int p0 = ptile * 2;
    const int P0 = (p0 + 55) % 56;   // source row for output p0   (roll +1 along p)
    const int P1 = p0;               // source row for output p0+1

    // 128 rows x 15 float4 = 30,720 B; staging rows S = (2g+m)*2 + q; store rows cr + 64*pl
    __shared__ float4 sm4[128 * 15];

    const int tid = threadIdx.x;
    const int pl = tid >> 8;         // which of the 2 output rows this thread computes
    const int t8 = tid & 255;
    const int h = t8 & 1;            // o-half: 0 -> o 0..27, 1 -> o 28..55
    const int c = t8 >> 1;           // output channel 0..127
    const int j = c >> 2;            // group
    const int k = c & 3;

    // ---- W loads first: L2-resident, latency hides under x staging ----
    float wt[3][2][3];
#pragma unroll
    for (int i = 0; i < 3; ++i)
#pragma unroll
        for (int m = 0; m < 2; ++m)
#pragma unroll
            for (int l = 0; l < 3; ++l)
                wt[i][m][l] = Wg[(((j * 3 + i) * 2 + m) * 3 + l) * 4 + k];

    // ---- stage: sm[S][v] = x[n, r, Pq, v] + x[n, r+64, Pq, v], S = 2r+q ----
    // 128 S-rows x 14 f4 = 1792; consecutive idx walk (P0,P1) adjacent rows -> 448B runs
    {
        const float4* x4 = reinterpret_cast<const float4*>(x);
#pragma unroll
        for (int it = 0; it < 4; ++it) {
            const int idx = tid + it * TPB;
            if (idx < 1792) {
                const int S = idx / 14;
                const int v = idx - S * 14;
                const int r = S >> 1;
                const int q = S & 1;
                const int Pq = q ? P1 : P0;
                const size_t base = (size_t)(n * 128 + r) * 784 + (size_t)Pq * 14 + (size_t)v;
                const float4 a = x4[base];
                const float4 b = x4[base + (size_t)64 * 784];
                float4 s;
                s.x = a.x + b.x; s.y = a.y + b.y; s.z = a.z + b.z; s.w = a.w + b.w;
                sm4[S * 15 + v] = s;
            }
        }
    }
    __syncthreads();

    // ---- compute: 28 outputs per thread, all-b128 LDS reads (verified R7 logic) ----
    // h=0: f4 {13, 0..6} -> cols {52..55, 0..27}; h=1: f4 {6..13} -> cols {24..55}
    // va[d] = fe[d+2]; fixups: h=0 -> va[0]=0 (o=0,l=0 pad); h=1 -> va[29]=0 (o=55,l=2 pad)
    const int q0 = h ? 6 : 13;
    const int qb = h ? 6 : -1;

    float acc[28];
#pragma unroll
    for (int u = 0; u < 28; ++u) acc[u] = 0.f;

#pragma unroll
    for (int i = 0; i < 3; ++i) {
        const int g = j + i - 1;
        if ((unsigned)g < 32u) {
#pragma unroll
            for (int m = 0; m < 2; ++m) {
                const float4* row4 = &sm4[((2 * g + m) * 2 + pl) * 15];
                float fe[32];
                {
                    const float4 t = row4[q0];
                    fe[0] = t.x; fe[1] = t.y; fe[2] = t.z; fe[3] = t.w;
                }
#pragma unroll
                for (int q = 1; q < 8; ++q) {
                    const float4 t = row4[qb + q];
                    fe[4 * q + 0] = t.x; fe[4 * q + 1] = t.y;
                    fe[4 * q + 2] = t.z; fe[4 * q + 3] = t.w;
                }
                float va[30];
#pragma unroll
                for (int d = 0; d < 30; ++d) va[d] = fe[d + 2];
                va[0]  = h ? va[0] : 0.f;
                va[29] = h ? 0.f : va[29];

                const float w0 = wt[i][m][0];
                const float w1 = wt[i][m][1];
                const float w2 = wt[i][m][2];
#pragma unroll
                for (int u = 0; u < 28; ++u)
                    acc[u] += w0 * va[u] + w1 * va[u + 1] + w2 * va[u + 2];
            }
        }
    }

    // ---- 2-pass transposed store, f4 throughout; store row = cr + 64*pl (odd f4 stride) ----
    const int chalf = c >> 6;
    const int cr = c & 63;
    float4* o4 = reinterpret_cast<float4*>(out);

#pragma unroll
    for (int half = 0; half < 2; ++half) {
        __syncthreads();             // staging/compute reads or previous pass reads done
        if (chalf == half) {
#pragma unroll
            for (int u4 = 0; u4 < 7; ++u4) {
                float4 v4;
                v4.x = acc[4 * u4 + 0];
                v4.y = acc[4 * u4 + 1];
                v4.z = acc[4 * u4 + 2];
                v4.w = acc[4 * u4 + 3];
                sm4[(cr + 64 * pl) * 15 + h * 7 + u4] = v4;
            }
        }
        __syncthreads();
        // 128 rows x 14 f4 = 1792; row ch' = cr + 64*pl -> out[n, 64*half+cr, p0+pl, :]
#pragma unroll
        for (int it = 0; it < 4; ++it) {
            const int idx = tid + it * TPB;
            if (idx < 1792) {
                const int chp = idx / 14;
                const int v = idx - chp * 14;
                const int scr = chp & 63;
                const int spl = chp >> 6;
                o4[(size_t)(n * 128 + half * 64 + scr) * 784 + (size_t)(p0 + spl) * 14 + (size_t)v] =
                    sm4[chp * 15 + v];
            }
        }
    }
}

extern "C" void kernel_launch(void* const* d_in, const int* in_sizes, int n_in,
                              void* d_out, int out_size, void* d_ws, size_t ws_size,
                              hipStream_t stream) {
    const float* x = (const float*)d_in[0];
    const float* W = (const float*)d_in[1];
    float* out = (float*)d_out;
    const int n = in_sizes[0] / (128 * 56 * 56);   // 128
    const int grid = n * 28;                        // one block per (n, 2-row p-tile)
    fused_shift_conv<<<grid, TPB, 0, stream>>>(x, W, out);
}

// Round 9
// 97.397 us; speedup vs baseline: 1.4221x; 1.4221x over previous
//
#include <hip/hip_runtime.h>

#define TPB 512

__global__ __launch_bounds__(TPB) void fused_shift_conv(const float* __restrict__ x,
                                                        const float* __restrict__ Wg,
                                                        float* __restrict__ out) {
    // block handles (n, 2 output rows p0, p0+1)
    const int bid = blockIdx.x;
    const int ptile = bid % 28;
    const int n = bid / 28;
    const int p0 = ptile * 2;
    const int P0 = (p0 + 55) % 56;   // source row for output p0   (roll +1 along p)
    const int P1 = p0;               // source row for output p0+1

    // 128 rows x 15 float4 = 30,720 B; staging rows S = 2r+q; store rows cr + 64*pl
    __shared__ float4 sm4[128 * 15];

    const int tid = threadIdx.x;
    const int pl = tid >> 8;         // which of the 2 output rows this thread computes
    const int t8 = tid & 255;
    const int h = t8 & 1;            // o-half: 0 -> o 0..27, 1 -> o 28..55
    const int c = t8 >> 1;           // output channel 0..127
    const int j = c >> 2;            // group
    const int k = c & 3;

    // ---- W loads first: L2-resident, latency hides under x staging ----
    float wt[3][2][3];
#pragma unroll
    for (int i = 0; i < 3; ++i)
#pragma unroll
        for (int m = 0; m < 2; ++m)
#pragma unroll
            for (int l = 0; l < 3; ++l)
                wt[i][m][l] = Wg[(((j * 3 + i) * 2 + m) * 3 + l) * 4 + k];

    // ---- stage: sm[S][v] = x[n, r, Pq, v] + x[n, r+64, Pq, v], S = 2r+q ----
    {
        const float4* x4 = reinterpret_cast<const float4*>(x);
#pragma unroll
        for (int it = 0; it < 4; ++it) {
            const int idx = tid + it * TPB;
            if (idx < 1792) {
                const int S = idx / 14;
                const int v = idx - S * 14;
                const int r = S >> 1;
                const int q = S & 1;
                const int Pq = q ? P1 : P0;
                const size_t base = (size_t)(n * 128 + r) * 784 + (size_t)Pq * 14 + (size_t)v;
                const float4 a = x4[base];
                const float4 b = x4[base + (size_t)64 * 784];
                float4 s;
                s.x = a.x + b.x; s.y = a.y + b.y; s.z = a.z + b.z; s.w = a.w + b.w;
                sm4[S * 15 + v] = s;
            }
        }
    }
    __syncthreads();

    // ---- compute: 28 outputs per thread, all-b128 LDS reads (verified R7 logic) ----
    // h=0: f4 {13, 0..6} -> cols {52..55, 0..27}; h=1: f4 {6..13} -> cols {24..55}
    // va[d] = fe[d+2]; fixups: h=0 -> va[0]=0 (o=0,l=0 pad); h=1 -> va[29]=0 (o=55,l=2 pad)
    const int q0 = h ? 6 : 13;
    const int qb = h ? 6 : -1;

    float acc[28];
#pragma unroll
    for (int u = 0; u < 28; ++u) acc[u] = 0.f;

#pragma unroll
    for (int i = 0; i < 3; ++i) {
        const int g = j + i - 1;
        if ((unsigned)g < 32u) {
#pragma unroll
            for (int m = 0; m < 2; ++m) {
                const float4* row4 = &sm4[((2 * g + m) * 2 + pl) * 15];
                float fe[32];
                {
                    const float4 t = row4[q0];
                    fe[0] = t.x; fe[1] = t.y; fe[2] = t.z; fe[3] = t.w;
                }
#pragma unroll
                for (int q = 1; q < 8; ++q) {
                    const float4 t = row4[qb + q];
                    fe[4 * q + 0] = t.x; fe[4 * q + 1] = t.y;
                    fe[4 * q + 2] = t.z; fe[4 * q + 3] = t.w;
                }
                float va[30];
#pragma unroll
                for (int d = 0; d < 30; ++d) va[d] = fe[d + 2];
                va[0]  = h ? va[0] : 0.f;
                va[29] = h ? 0.f : va[29];

                const float w0 = wt[i][m][0];
                const float w1 = wt[i][m][1];
                const float w2 = wt[i][m][2];
#pragma unroll
                for (int u = 0; u < 28; ++u)
                    acc[u] += w0 * va[u] + w1 * va[u + 1] + w2 * va[u + 2];
            }
        }
    }

    // ---- 2-pass transposed store, f4 throughout; store row = cr + 64*pl (odd f4 stride) ----
    const int chalf = c >> 6;
    const int cr = c & 63;
    float4* o4 = reinterpret_cast<float4*>(out);

#pragma unroll
    for (int half = 0; half < 2; ++half) {
        __syncthreads();             // staging/compute reads or previous pass reads done
        if (chalf == half) {
#pragma unroll
            for (int u4 = 0; u4 < 7; ++u4) {
                float4 v4;
                v4.x = acc[4 * u4 + 0];
                v4.y = acc[4 * u4 + 1];
                v4.z = acc[4 * u4 + 2];
                v4.w = acc[4 * u4 + 3];
                sm4[(cr + 64 * pl) * 15 + h * 7 + u4] = v4;
            }
        }
        __syncthreads();
        // 128 rows x 14 f4 = 1792; row ch' = cr + 64*pl -> out[n, 64*half+cr, p0+pl, :]
#pragma unroll
        for (int it = 0; it < 4; ++it) {
            const int idx = tid + it * TPB;
            if (idx < 1792) {
                const int chp = idx / 14;
                const int v = idx - chp * 14;
                const int scr = chp & 63;
                const int spl = chp >> 6;
                o4[(size_t)(n * 128 + half * 64 + scr) * 784 + (size_t)(p0 + spl) * 14 + (size_t)v] =
                    sm4[chp * 15 + v];
            }
        }
    }
}

extern "C" void kernel_launch(void* const* d_in, const int* in_sizes, int n_in,
                              void* d_out, int out_size, void* d_ws, size_t ws_size,
                              hipStream_t stream) {
    const float* x = (const float*)d_in[0];
    const float* W = (const float*)d_in[1];
    float* out = (float*)d_out;
    const int n = in_sizes[0] / (128 * 56 * 56);   // 128
    const int grid = n * 28;                        // one block per (n, 2-row p-tile)
    fused_shift_conv<<<grid, TPB, 0, stream>>>(x, W, out);
}